// Round 3
// baseline (396.402 us; speedup 1.0000x reference)
//
#include <hip/hip_runtime.h>

typedef short bf16x8 __attribute__((ext_vector_type(8)));
typedef float f32x4  __attribute__((ext_vector_type(4)));

namespace {

constexpr int CIN = 32, CO = 32, Himg = 128, Wimg = 128, SY = 32, Bb = 4;
constexpr int IMG = Himg * Wimg;                 // 16384
constexpr int NT  = Bb * CO * IMG;               // new_target elems
constexpr int TROWS = 6, TQ = 17, TCOLS = 70;    // 6 rows x 17 col-quads staged
constexpr int NPIX  = TROWS * TCOLS;             // 420
constexpr int LDSB  = NPIX * 64;                 // 26880 B ([pixel][ci] bf16)
constexpr int RTASK = TROWS * TQ;                // 102 (row,quad) pairs
constexpr int TPT   = 7;                         // tasks per thread (256 thr)

__device__ __forceinline__ int swz(int pix, int cb) {
  return (pix * 64 + cb) ^ ((pix & 7) << 4);
}
__device__ __forceinline__ unsigned cvtpk(float lo, float hi) {
  unsigned r;
  asm("v_cvt_pk_bf16_f32 %0, %1, %2" : "=v"(r) : "v"(lo), "v"(hi));
  return r;
}

// task decode: t -> (ch, row, q); ch-fastest for conflict-free LDS writes
__device__ __forceinline__ void task_decode(int t, int& ch, int& row, int& q, bool& act) {
  ch = t & 15;
  const int r = t >> 4;
  row = r / TQ;
  q   = r - row * TQ;
  act = (r < RTASK);
}

// burst-issue all global loads for one tile into registers (aligned float4)
__device__ __forceinline__ void stage_load(f32x4 va[TPT], f32x4 vb[TPT],
                                           const float* __restrict__ src,
                                           int y0, int xq0, int tid)
{
  #pragma unroll
  for (int k = 0; k < TPT; ++k) {
    int ch, row, q; bool act;
    task_decode(tid + k * 256, ch, row, q, act);
    const int y = y0 - 1 + row;
    act = act && ((unsigned)y < (unsigned)Himg);
    f32x4 v0 = {0.f, 0.f, 0.f, 0.f}, v1 = {0.f, 0.f, 0.f, 0.f};
    if (act) {
      const float* p = src + (size_t)(2 * ch) * IMG + y * Wimg + 4 * (xq0 + q);
      v0 = *reinterpret_cast<const f32x4*>(p);
      v1 = *reinterpret_cast<const f32x4*>(p + IMG);
    }
    va[k] = v0; vb[k] = v1;
  }
}

// convert + write the staged registers to LDS (swizzled [pixel][ci] bf16)
__device__ __forceinline__ void stage_write(const f32x4 va[TPT], const f32x4 vb[TPT],
                                            char* __restrict__ lds,
                                            int y0, int xq0, int x0, int tid)
{
  #pragma unroll
  for (int k = 0; k < TPT; ++k) {
    int ch, row, q; bool act;
    task_decode(tid + k * 256, ch, row, q, act);
    const int y = y0 - 1 + row;
    act = act && ((unsigned)y < (unsigned)Himg);
    if (act) {
      const int ix0 = 4 * (xq0 + q) - x0 + 1;   // lds column of elem 0
      #pragma unroll
      for (int e = 0; e < 4; ++e) {
        const int ix = ix0 + e;
        if (ix >= 0) {
          const int pix = row * TCOLS + ix;
          *reinterpret_cast<unsigned*>(lds + swz(pix, ch * 4)) =
              cvtpk(va[k][e], vb[k][e]);
        }
      }
    }
  }
}

// per-lane A fragments (weights), 9 taps x 2 co-tiles; ci = kc*8 + j
__device__ __forceinline__ void load_w(bf16x8 wf[9][2],
                                       const float* __restrict__ Wfull,
                                       int cioff, int lane)
{
  const int lx = lane & 15, kc = lane >> 4;
  #pragma unroll
  for (int tap = 0; tap < 9; ++tap) {
    #pragma unroll
    for (int m = 0; m < 2; ++m) {
      const float* base = Wfull + (size_t)((m * 16 + lx) * 64 + cioff + kc * 8) * 9 + tap;
      bf16x8 w;
      #pragma unroll
      for (int j = 0; j < 8; ++j) {
        unsigned u = __builtin_bit_cast(unsigned, base[j * 9]);
        w[j] = (short)((u + 0x7FFFu + ((u >> 16) & 1u)) >> 16);
      }
      wf[tap][m] = w;
    }
  }
}

__device__ __forceinline__ void conv(f32x4 acc[2][4],
                                     const char* __restrict__ lds,
                                     const bf16x8 wf[9][2],
                                     int wrow, int lane)
{
  const int lx = lane & 15, kc = lane >> 4;
  #pragma unroll
  for (int ky = 0; ky < 3; ++ky) {
    #pragma unroll
    for (int kx = 0; kx < 3; ++kx) {
      const int tap = ky * 3 + kx;
      #pragma unroll
      for (int n = 0; n < 4; ++n) {
        const int p = (wrow + ky) * TCOLS + n * 16 + lx + kx;
        const bf16x8 bfrag = *reinterpret_cast<const bf16x8*>(lds + swz(p, kc * 16));
        acc[0][n] = __builtin_amdgcn_mfma_f32_16x16x32_bf16(wf[tap][0], bfrag, acc[0][n], 0, 0, 0);
        acc[1][n] = __builtin_amdgcn_mfma_f32_16x16x32_bf16(wf[tap][1], bfrag, acc[1][n], 0, 0, 0);
      }
    }
  }
}

__global__ __launch_bounds__(256, 2)
void cross_mfma(const float* __restrict__ target,
                const float* __restrict__ support,
                const float* __restrict__ Wfull,
                const float* __restrict__ bias,
                float* __restrict__ out)
{
  __shared__ char lds[LDSB];

  const int tid  = threadIdx.x;
  const int lane = tid & 63;
  const int wrow = tid >> 6;
  const int lx = lane & 15, kc = lane >> 4;

  const int bid = blockIdx.x;
  const int syh = bid & 1;
  const int xh  = (bid >> 1) & 1;
  const int yb  = (bid >> 2) & 31;
  const int b   = bid >> 7;
  const int y0 = yb * 4, x0 = xh * 64;
  const int y  = y0 + wrow;
  const int xq0 = xh ? 15 : 0;   // first aligned source quad

  // zero LDS once; statically-OOB cells (image border, pad cols) stay zero
  for (int e = tid; e < NPIX * 4; e += 256)
    reinterpret_cast<f32x4*>(lds)[e] = f32x4{0.f, 0.f, 0.f, 0.f};

  bf16x8 wf[9][2];
  load_w(wf, Wfull, 0, lane);                       // Wx

  f32x4 va[TPT], vb[TPT];
  stage_load(va, vb, target + (size_t)b * CIN * IMG, y0, xq0, tid);
  __syncthreads();                                  // zero-fill complete
  stage_write(va, vb, lds, y0, xq0, x0, tid);
  __syncthreads();                                  // target tile ready

  // cx = conv(target, Wx) + bias, reused across all sy
  f32x4 cx[2][4];
  #pragma unroll
  for (int m = 0; m < 2; ++m)
    #pragma unroll
    for (int n = 0; n < 4; ++n) cx[m][n] = f32x4{0.f, 0.f, 0.f, 0.f};
  conv(cx, lds, wf, wrow, lane);
  #pragma unroll
  for (int m = 0; m < 2; ++m)
    #pragma unroll
    for (int j = 0; j < 4; ++j) {
      const float bv = bias[m * 16 + kc * 4 + j];
      #pragma unroll
      for (int n = 0; n < 4; ++n) cx[m][n][j] += bv;
    }

  const float* supp0 = support + (size_t)(b * SY + syh * 16) * CIN * IMG;
  stage_load(va, vb, supp0, y0, xq0, tid);          // issue sy=0 burst early
  load_w(wf, Wfull, 32, lane);                      // switch to Wy
  __syncthreads();                                  // target-tile reads done
  stage_write(va, vb, lds, y0, xq0, x0, tid);

  f32x4 sum[2][4];
  #pragma unroll
  for (int m = 0; m < 2; ++m)
    #pragma unroll
    for (int n = 0; n < 4; ++n) sum[m][n] = f32x4{0.f, 0.f, 0.f, 0.f};
  __syncthreads();                                  // sy=0 tile ready

  for (int i = 0; i < 16; ++i) {
    if (i < 15)                                     // burst-issue next tile
      stage_load(va, vb, supp0 + (size_t)(i + 1) * CIN * IMG, y0, xq0, tid);

    f32x4 acc[2][4];
    #pragma unroll
    for (int m = 0; m < 2; ++m)
      #pragma unroll
      for (int n = 0; n < 4; ++n) acc[m][n] = cx[m][n];
    conv(acc, lds, wf, wrow, lane);
    __syncthreads();                                // all reads of tile i done

    if (i < 15)
      stage_write(va, vb, lds, y0, xq0, x0, tid);   // vmcnt wait hides here

    const int sy = syh * 16 + i;
    #pragma unroll
    for (int m = 0; m < 2; ++m)
      #pragma unroll
      for (int n = 0; n < 4; ++n) {
        sum[m][n] += acc[m][n];
        const size_t basei = (size_t)NT +
            (((size_t)(b * SY + sy) * CO + m * 16 + kc * 4) * Himg + y) * Wimg +
            x0 + n * 16 + lx;
        #pragma unroll
        for (int j = 0; j < 4; ++j)
          __builtin_nontemporal_store(acc[m][n][j], &out[basei + (size_t)j * IMG]);
      }
    __syncthreads();                                // tile i+1 written
  }

  // new_target = cx + bias + mean_sy(cy); 2 partial adds per element
  #pragma unroll
  for (int m = 0; m < 2; ++m)
    #pragma unroll
    for (int n = 0; n < 4; ++n) {
      const size_t baseo =
          ((size_t)(b * CO + m * 16 + kc * 4) * Himg + y) * Wimg + x0 + n * 16 + lx;
      #pragma unroll
      for (int j = 0; j < 4; ++j) {
        const float cyPart = (sum[m][n][j] - 16.f * cx[m][n][j]) * (1.f / 32.f);
        const float v = cyPart + (syh == 0 ? cx[m][n][j] : 0.f);
        atomicAdd(&out[baseo + (size_t)j * IMG], v);
      }
    }
}

} // namespace

extern "C" void kernel_launch(void* const* d_in, const int* in_sizes, int n_in,
                              void* d_out, int out_size, void* d_ws, size_t ws_size,
                              hipStream_t stream)
{
  (void)in_sizes; (void)n_in; (void)out_size; (void)d_ws; (void)ws_size;
  const float* target  = (const float*)d_in[0];
  const float* support = (const float*)d_in[1];
  const float* Wfull   = (const float*)d_in[2];
  const float* bias    = (const float*)d_in[3];
  float* out = (float*)d_out;

  hipMemsetAsync(d_out, 0, (size_t)NT * sizeof(float), stream);
  cross_mfma<<<dim3(512), 256, 0, stream>>>(target, support, Wfull, bias, out);
}